// Round 16
// baseline (285.094 us; speedup 1.0000x reference)
//
#include <hip/hip_runtime.h>
#include <math.h>

// Round 21: attn_fused SBLK 64->128 — halve the barrier count (the measured
// ~70% of block time). Phase A: 4 phases x 128 s-rows (7 barriers, was 15);
// Phase B: 4 V-chunks x 128 s (7, was 15). 8 MFMAs/wave/phase amortize each
// drain. LDS kept at 3 blocks/CU by dropping Qs (Q frags direct, once) and
// mk (mask direct in stats) — both proven safe (R14/R16): Ws 33.3K + KVs
// 18.4K (128x72 K-tiles / 64x136 V-chunks) = 51.8K. Everything else
// byte-identical to round 20 (best = 281.9us).

typedef short bf8 __attribute__((ext_vector_type(8)));
typedef short bf4 __attribute__((ext_vector_type(4)));
typedef float f32x4 __attribute__((ext_vector_type(4)));
typedef unsigned short u16;

constexpr int LDT = 40;  // LDS row stride in shorts (32 data + 8 pad)
#define RSQRT2 0.70710678118654752f

__device__ __forceinline__ u16 f2bf(float f) {
  unsigned int u = __builtin_bit_cast(unsigned int, f);
  unsigned int r = u + 0x7fffu + ((u >> 16) & 1u);  // RNE
  return (u16)(r >> 16);
}
__device__ __forceinline__ float bf2f(u16 v) {
  return __builtin_bit_cast(float, (unsigned int)v << 16);
}
__device__ __forceinline__ f32x4 mfma16(bf8 a, bf8 b, f32x4 c) {
  return __builtin_amdgcn_mfma_f32_16x16x32_bf16(a, b, c, 0, 0, 0);
}

// ------- batched f32 -> bf16 conversion + index compaction (merged) ---------
struct CvtDesc { const float* src; u16* dst; int n; };
struct CvtArgs { CvtDesc d[8]; int blk0[9]; };  // blk0: prefix block starts

__global__ __launch_bounds__(256) void cvt_k(
    CvtArgs a, const int* __restrict__ pm, const int* __restrict__ batch,
    int* __restrict__ list, int* __restrict__ inv, int* __restrict__ cnt,
    int N) {
  const int blk = blockIdx.x;
  if (blk >= a.blk0[8]) {  // ---- compact tail blocks ----
    int m = (blk - a.blk0[8]) * 256 + threadIdx.x;
    if (m >= N) return;
    int p = pm[m];
    int b = batch[p];
    int slot = atomicAdd(&cnt[b], 1);
    list[(size_t)b * N + slot] = m;
    inv[p] = m;
    return;
  }
  int d = 0;
#pragma unroll
  for (int k = 1; k < 8; ++k)
    if (blk >= a.blk0[k]) d = k;
  CvtDesc dd = a.d[d];
  int i = ((blk - a.blk0[d]) * 256 + threadIdx.x) * 8;
  if (i >= dd.n) return;
  f32x4 v0 = *(const f32x4*)(dd.src + i);
  f32x4 v1 = *(const f32x4*)(dd.src + i + 4);
  bf8 o;
  o[0] = (short)f2bf(v0[0]); o[1] = (short)f2bf(v0[1]);
  o[2] = (short)f2bf(v0[2]); o[3] = (short)f2bf(v0[3]);
  o[4] = (short)f2bf(v1[0]); o[5] = (short)f2bf(v1[1]);
  o[6] = (short)f2bf(v1[2]); o[7] = (short)f2bf(v1[3]);
  *(bf8*)(dd.dst + i) = o;
}

// ---------------- index init (list=-1, inv=-1, cnt=0) ------------------------
__global__ void init_idx_k(int* __restrict__ list, int* __restrict__ inv,
                           int* __restrict__ cnt, int N, int B) {
  int i = blockIdx.x * 256 + threadIdx.x;
  if (i < B * N) list[i] = -1;
  if (i < N) inv[i] = -1;
  if (i < B) cnt[i] = 0;
}

// ------- 64x64-tile bf16 GEMM body (dbuf LDS + reg prefetch) -----------------
// C[M,Nn](bf16) = A[M,K](bf16, optional row gather) @ B[Nn,K](bf16)^T
// If VTout != nullptr: cols >= 512 are written TRANSPOSED into VTout as
// VTout[((row>>9)*512 + col-512)*512 + (row&511)] (one bf4 store per (i,j)).
__device__ __forceinline__ void proj64_body(
    u16 (*As)[64 * LDT], u16 (*Bs)[64 * LDT],
    const u16* __restrict__ A, const u16* __restrict__ B,
    u16* __restrict__ C, int M, int Nn, int K, int lda, int ldb, int ldc,
    const int* __restrict__ gatherA, int m0, int n0, u16* __restrict__ VTout) {
  const int tid = threadIdx.x;
  const int wave = tid >> 6, lane = tid & 63;
  const int wm = (wave & 1) * 32, wn = (wave >> 1) * 32;
  const int lrow = lane & 15, quad = lane >> 4;
  const int srow = tid >> 2, skq = tid & 3;
  const bf8 z8 = {0, 0, 0, 0, 0, 0, 0, 0};
  const int off = srow * LDT + skq * 8;

  int gr0 = m0 + srow;
  int ar0 = (gr0 < M) ? (gatherA ? gatherA[gr0] : gr0) : -1;
  const u16* Ap0 = (ar0 >= 0) ? A + (size_t)ar0 * lda + skq * 8 : nullptr;
  const u16* Bp = (n0 + srow < Nn) ? B + (size_t)(n0 + srow) * ldb + skq * 8 : nullptr;

  // prologue: stage k=0 into buffer 0
  {
    bf8 a0 = Ap0 ? *(const bf8*)Ap0 : z8;
    bf8 bv = Bp ? *(const bf8*)Bp : z8;
    *(bf8*)&As[0][off] = a0;
    *(bf8*)&Bs[0][off] = bv;
  }
  __syncthreads();

  f32x4 acc[2][2];
#pragma unroll
  for (int i = 0; i < 2; ++i)
#pragma unroll
    for (int j = 0; j < 2; ++j) acc[i][j] = (f32x4){0.f, 0.f, 0.f, 0.f};

  int cur = 0;
  for (int k0 = 0; k0 < K; k0 += 32) {
    const bool more = (k0 + 32 < K);
    bf8 na, nb;
    if (more) {  // issue next-tile loads; consumed after the MFMAs
      na = Ap0 ? *(const bf8*)(Ap0 + k0 + 32) : z8;
      nb = Bp ? *(const bf8*)(Bp + k0 + 32) : z8;
    }
    bf8 af0 = *(const bf8*)&As[cur][(wm + lrow) * LDT + quad * 8];
    bf8 af1 = *(const bf8*)&As[cur][(wm + 16 + lrow) * LDT + quad * 8];
    bf8 bf0 = *(const bf8*)&Bs[cur][(wn + lrow) * LDT + quad * 8];
    bf8 bf1 = *(const bf8*)&Bs[cur][(wn + 16 + lrow) * LDT + quad * 8];
    acc[0][0] = mfma16(af0, bf0, acc[0][0]);
    acc[0][1] = mfma16(af0, bf1, acc[0][1]);
    acc[1][0] = mfma16(af1, bf0, acc[1][0]);
    acc[1][1] = mfma16(af1, bf1, acc[1][1]);
    if (more) {  // write next tile into the OTHER buffer (no fence needed)
      *(bf8*)&As[cur ^ 1][off] = na;
      *(bf8*)&Bs[cur ^ 1][off] = nb;
    }
    __syncthreads();
    cur ^= 1;
  }

#pragma unroll
  for (int i = 0; i < 2; ++i) {
    const int row0 = m0 + wm + i * 16 + quad * 4;  // r = 0..3 consecutive
#pragma unroll
    for (int j = 0; j < 2; ++j) {
      int col = n0 + wn + j * 16 + lrow;
      if (col >= Nn) continue;
      if (VTout && col >= 512) {
        // transposed V write: 4 consecutive s positions -> one 8B store
        if (row0 < M) {
          int b = row0 >> 9, sl = row0 & 511;
          bf4 o;
#pragma unroll
          for (int r = 0; r < 4; ++r) o[r] = (short)f2bf(acc[i][j][r]);
          *(bf4*)&VTout[((size_t)(b * 512 + (col - 512)) * 512) + sl] = o;
        }
        continue;
      }
#pragma unroll
      for (int r = 0; r < 4; ++r) {
        int row = row0 + r;
        if (row >= M) continue;
        if (gatherA && gatherA[row] < 0) continue;
        C[(size_t)row * ldc + col] = f2bf(acc[i][j][r]);
      }
    }
  }
}

// ------- merged KV-proj (blocks [0,512)) + Q-proj (blocks [512,1024)) -------
__global__ __launch_bounds__(256) void qkvproj_k(
    const u16* __restrict__ embbf, const u16* __restrict__ Wkvbf,
    u16* __restrict__ KVbf, u16* __restrict__ VT,
    const u16* __restrict__ xbf, const u16* __restrict__ Wqbf,
    u16* __restrict__ Qbf, const int* __restrict__ pm,
    int MKV, int N, int nkv) {
  __shared__ __align__(16) u16 As[2][64 * LDT];
  __shared__ __align__(16) u16 Bs[2][64 * LDT];
  const int blk = blockIdx.x;
  if (blk < nkv) {  // KV: MKV x 1024, K=1280; n-tiles = 16 (8 K + 8 V)
    int by = blk >> 4, bx = blk & 15;
    proj64_body(As, Bs, embbf, Wkvbf, KVbf, MKV, 1024, 1280, 1280, 1280, 1024,
                nullptr, by * 64, bx * 64, VT);
  } else {          // Q: N x 512, K=256, gather pm; n-tiles = 8
    int t = blk - nkv;
    int by = t >> 3, bx = t & 7;
    proj64_body(As, Bs, xbf, Wqbf, Qbf, N, 512, 256, 256, 256, 512,
                pm, by * 64, bx * 64, nullptr);
  }
}

// ---------------- fused attention: per (b,h,mtile32) -------------------------
// SBLK=128: Phase A = 4 phases x 128 s-rows; Phase B = 4 V-chunks x 128 s.
// Q fragments + mask direct from global; XCD swizzle; k-rotation mod 4.
constexpr int WST = 520;  // W row stride (512 + 8 pad) -> 65 granules (odd)
constexpr int KST = 72;   // K tile row stride (64k + 8) -> 9 granules (odd)
constexpr int VST = 136;  // V chunk row stride (128s + 8) -> 17 granules (odd)

__global__ __launch_bounds__(256) void attn_fused(
    const u16* __restrict__ Q, const u16* __restrict__ KV,
    const u16* __restrict__ VT, const int* __restrict__ list,
    const float* __restrict__ mask, u16* __restrict__ packed,
    u16* __restrict__ feat, int N) {
  const int NMT = gridDim.x;              // mt tiles per (b,h)
  const int lin = blockIdx.y * NMT + blockIdx.x;
  const int xcd = lin & 7, rest = lin >> 3;
  const int mt = rest % NMT;
  const int y = ((rest / NMT) << 3) | xcd;
  const int b = y >> 3, h = y & 7;
  const int* lst = list + (size_t)b * N + mt * 32;
  if (lst[0] < 0) return;

  __shared__ __align__(16) u16 Ws[32 * WST];
  __shared__ __align__(16) u16 KVs[128 * KST];  // K tiles; V chunks use 64*VST
  __shared__ int mS[32];

  const int tid = threadIdx.x;
  const int wave = tid >> 6, lane = tid & 63;
  const int wm = (wave & 1) * 16;
  const int wsn = (wave >> 1) * 64;   // phase-A s range (64 per wave pair)
  const int wnd = (wave >> 1) * 32;   // phase-B d range
  const int lrow = lane & 15, quad = lane >> 4;
  const bf8 z8 = {0, 0, 0, 0, 0, 0, 0, 0};

  const u16* KVb = KV + (size_t)(b * 512) * 1024 + h * 64;
  const u16* VTb = VT + (size_t)(b * 512 + h * 64) * 512;

  if (tid < 32) mS[tid] = lst[tid];
  {  // prologue: stage K tile rot(0): 128 rows x 64k, 4 bf8/thread
    int sta = mt & 3;
#pragma unroll
    for (int i = 0; i < 4; ++i) {
      int c = tid * 4 + i, sr = c >> 3, kq = c & 7;
      *(bf8*)&KVs[sr * KST + kq * 8] =
          *(const bf8*)(KVb + (size_t)(sta * 128 + sr) * 1024 + kq * 8);
    }
  }
  __syncthreads();

  // Q fragments direct from global (one 2x16B read per lane, never re-read)
  const int qrow = mS[wm + lrow];
  const u16* Qr = Q + (size_t)qrow * 512 + h * 64 + quad * 8;
  const bf8 qa0 = (qrow >= 0) ? *(const bf8*)Qr : z8;
  const bf8 qa1 = (qrow >= 0) ? *(const bf8*)(Qr + 32) : z8;

  // ---- Phase A: scores; 4 phases x 128 s; next tile reg-prefetched ----
  bf8 ra[4];
  for (int st = 0; st < 4; ++st) {
    const int sta = (st + mt) & 3;
    if (st < 3) {  // issue next-tile loads; drained at the barrier below
      int nxt = (st + 1 + mt) & 3;
#pragma unroll
      for (int i = 0; i < 4; ++i) {
        int c = tid * 4 + i, sr = c >> 3, kq = c & 7;
        ra[i] = *(const bf8*)(KVb + (size_t)(nxt * 128 + sr) * 1024 + kq * 8);
      }
    }
    f32x4 acc[4];
#pragma unroll
    for (int sf = 0; sf < 4; ++sf) acc[sf] = (f32x4){0.f, 0.f, 0.f, 0.f};
    __builtin_amdgcn_s_setprio(1);
#pragma unroll
    for (int sf = 0; sf < 4; ++sf) {
      int scol = wsn + sf * 16;
      bf8 b0 = *(const bf8*)&KVs[(scol + lrow) * KST + quad * 8];
      bf8 b1 = *(const bf8*)&KVs[(scol + lrow) * KST + 32 + quad * 8];
      acc[sf] = mfma16(qa0, b0, acc[sf]);
      acc[sf] = mfma16(qa1, b1, acc[sf]);
    }
    __builtin_amdgcn_s_setprio(0);
#pragma unroll
    for (int sf = 0; sf < 4; ++sf) {
      int scol = wsn + sf * 16;
#pragma unroll
      for (int r = 0; r < 4; ++r) {
        int lr = wm + quad * 4 + r;
        Ws[lr * WST + (sta << 7) + scol + lrow] = f2bf(acc[sf][r] * 0.125f);
      }
    }
    __syncthreads();  // KVs reads done + Ws visible (+ ra arrived)
    if (st < 3) {
#pragma unroll
      for (int i = 0; i < 4; ++i) {
        int c = tid * 4 + i, sr = c >> 3, kq = c & 7;
        *(bf8*)&KVs[sr * KST + kq * 8] = ra[i];
      }
      __syncthreads();  // next tile ready
    }
  }

  // Phase-B prologue: first V chunk (64d x 128s) to regs; hidden under stats
  bf8 vp[4];
  {
    int s0 = (mt & 3) << 7;
#pragma unroll
    for (int i = 0; i < 4; ++i) {
      int c = tid * 4 + i, vr = c >> 4, vq = c & 15;
      vp[i] = *(const bf8*)(VTb + (size_t)vr * 512 + s0 + vq * 8);
    }
  }

  // ---- Stats + W rebuild: mask direct from global; ev cached in VGPRs ----
  {
    const int row = tid >> 3, part = tid & 7;
    u16* wrow = &Ws[row * WST + part * 64];
    const int mm = mS[row];
    const float* mkp = mask + (size_t)b * 512 + part * 64;
    bf8 w[8];
    float mx = -1e30f;
#pragma unroll
    for (int v = 0; v < 8; ++v) {
      w[v] = *(const bf8*)(wrow + v * 8);
#pragma unroll
      for (int j = 0; j < 8; ++j) mx = fmaxf(mx, bf2f((u16)w[v][j]));
    }
    if (mm >= 0) {  // packed raw scores, 16B coalesced stores
      u16* prow = packed + ((size_t)h * N + mm) * 512 + part * 64;
#pragma unroll
      for (int v = 0; v < 8; ++v) *(bf8*)(prow + v * 8) = w[v];
    }
#pragma unroll
    for (int d = 1; d < 8; d <<= 1) mx = fmaxf(mx, __shfl_xor(mx, d));
    float ev[64];
    float se = 0.f, ms = 0.f;
#pragma unroll
    for (int v = 0; v < 8; ++v) {
      f32x4 m0 = *(const f32x4*)(mkp + v * 8);
      f32x4 m1 = *(const f32x4*)(mkp + v * 8 + 4);
#pragma unroll
      for (int j = 0; j < 8; ++j) {
        float e = __expf(bf2f((u16)w[v][j]) - mx);
        ev[v * 8 + j] = e;
        se += e;
        ms += e * (j < 4 ? m0[j] : m1[j - 4]);
      }
    }
#pragma unroll
    for (int d = 1; d < 8; d <<= 1) {
      se += __shfl_xor(se, d);
      ms += __shfl_xor(ms, d);
    }
    float iv = 1.0f / (ms + 1e-6f * se);
#pragma unroll
    for (int v = 0; v < 8; ++v) {
      f32x4 m0 = *(const f32x4*)(mkp + v * 8);
      f32x4 m1 = *(const f32x4*)(mkp + v * 8 + 4);
      bf8 o;
#pragma unroll
      for (int j = 0; j < 8; ++j)
        o[j] = (short)f2bf(ev[v * 8 + j] * (j < 4 ? m0[j] : m1[j - 4]) * iv);
      *(bf8*)(wrow + v * 8) = o;
    }
  }
  __syncthreads();  // Ws rebuilt visible; Phase-A KVs reads long done
#pragma unroll
  for (int i = 0; i < 4; ++i) {  // write V chunk rot(0)
    int c = tid * 4 + i, vr = c >> 4, vq = c & 15;
    *(bf8*)&KVs[vr * VST + vq * 8] = vp[i];
  }
  __syncthreads();  // V chunk ready

  // ---- Phase B: feat = W @ VT^T (32m x 64d), 4 chunks x 128 s ----
  f32x4 acc0 = {0.f, 0.f, 0.f, 0.f}, acc1 = acc0;
  for (int ss = 0; ss < 4; ++ss) {
    const int s0 = ((ss + mt) & 3) << 7;
    if (ss < 3) {  // issue next-chunk loads; drained at the barrier below
      int nx = ((ss + 1 + mt) & 3) << 7;
#pragma unroll
      for (int i = 0; i < 4; ++i) {
        int c = tid * 4 + i, vr = c >> 4, vq = c & 15;
        vp[i] = *(const bf8*)(VTb + (size_t)vr * 512 + nx + vq * 8);
      }
    }
    __builtin_amdgcn_s_setprio(1);
#pragma unroll
    for (int kk = 0; kk < 4; ++kk) {
      bf8 a = *(const bf8*)&Ws[(wm + lrow) * WST + s0 + kk * 32 + quad * 8];
      bf8 b0 = *(const bf8*)&KVs[(wnd + lrow) * VST + kk * 32 + quad * 8];
      bf8 b1 = *(const bf8*)&KVs[(wnd + 16 + lrow) * VST + kk * 32 + quad * 8];
      acc0 = mfma16(a, b0, acc0);
      acc1 = mfma16(a, b1, acc1);
    }
    __builtin_amdgcn_s_setprio(0);
    __syncthreads();  // KVs reads done (+ vp arrived)
    if (ss < 3) {
#pragma unroll
      for (int i = 0; i < 4; ++i) {
        int c = tid * 4 + i, vr = c >> 4, vq = c & 15;
        *(bf8*)&KVs[vr * VST + vq * 8] = vp[i];
      }
      __syncthreads();  // next chunk ready
    }
  }
#pragma unroll
  for (int r = 0; r < 4; ++r) {
    int lr = wm + quad * 4 + r;
    int mm = mS[lr];
    if (mm < 0) continue;
    u16* frow = feat + (size_t)mm * 512 + h * 64;
    frow[wnd + lrow] = f2bf(acc0[r]);
    frow[wnd + 16 + lrow] = f2bf(acc1[r]);
  }
}

// ------- merged: mlp chain (blocks < nmlp) + unpack (blocks >= nmlp) ---------
constexpr int HST = 268;   // Hs row stride in floats (67 granules, odd)
constexpr int AST = 520;   // As row stride in shorts (65 granules, odd)
constexpr int YST = 280;   // Ys row stride in shorts (35 granules, odd)
constexpr int SMEM_BYTES = 16 * HST * 4 + 16 * AST * 2 + 16 * YST * 2;

__global__ __launch_bounds__(1024) void mlp_unpack(
    const u16* __restrict__ feat, const float* __restrict__ ag_s,
    const float* __restrict__ ag_b, const u16* __restrict__ Wag,
    const float* __restrict__ x, const float* __restrict__ ens,
    const float* __restrict__ enb, const float* __restrict__ rls,
    const float* __restrict__ rlb, const u16* __restrict__ rw1,
    const float* __restrict__ rb1, const u16* __restrict__ rw2,
    const float* __restrict__ rb2, const float* __restrict__ hw,
    const float* __restrict__ hb, const int* __restrict__ pm,
    const u16* __restrict__ packed, float* __restrict__ out_sc,
    float* __restrict__ out_lg, float* __restrict__ out_x,
    int nmlp, int N) {
  __shared__ __align__(16) char smem[SMEM_BYTES];
  const int tid = threadIdx.x;

  if (blockIdx.x >= nmlp) {
    // ---------------- unpack body: 4 m-rows, 256 threads each ----------------
    u16* Ls = (u16*)smem;  // [4][8*520]
    const int g = tid >> 8, t = tid & 255;
    const int m = (blockIdx.x - nmlp) * 4 + g;
    u16* Lg = Ls + g * (8 * 520);
    int h = t >> 5, c = (t & 31) * 16;
    const u16* row = packed + ((size_t)h * N + m) * 512 + c;
    *(bf8*)&Lg[h * 520 + c] = *(const bf8*)row;
    *(bf8*)&Lg[h * 520 + c + 8] = *(const bf8*)(row + 8);
    __syncthreads();
    float* orow = out_sc + (size_t)pm[m] * 4096;
#pragma unroll
    for (int i = 0; i < 16; ++i) {
      int e = t + i * 256;
      orow[e] = bf2f(Lg[(e & 7) * 520 + (e >> 3)]);
    }
    return;
  }

  // ------------------------------ mlp body -----------------------------------
  float* Hs = (float*)smem;
  u16* As = (u16*)(smem + 16 * HST * 4);
  u16* Ys = (u16*)(smem + 16 * HST * 4 + 16 * AST * 2);
  const int m0 = blockIdx.x * 16;
  const int wave = tid >> 6, lane = tid & 63;
  const int lrow = lane & 15, quad = lane >> 4;
  const int wn = wave * 16;
  const int row = wave;
  const int wq8 = quad * 8;
  const int nrow = pm[m0 + row];

  const u16* WagW = Wag + (size_t)(wn + lrow) * 512 + wq8;
  const u16* W1W = rw1 + (size_t)(wn + lrow) * 256 + wq8;
  const u16* W2W = rw2 + (size_t)(wn + lrow) * 256 + wq8;

  bf8 wp[8];
#pragma unroll
  for (int i = 0; i < 8; ++i) wp[i] = *(const bf8*)(WagW + i * 32);

  // ---- LN512(feat) -> As (bf16), 8 cols per lane ----
  {
    const u16* frow = feat + (size_t)(m0 + row) * 512 + lane * 8;
    bf8 f0 = *(const bf8*)frow;
    float s = 0.f, sq = 0.f;
#pragma unroll
    for (int j = 0; j < 8; ++j) {
      float a = bf2f((u16)f0[j]);
      s += a;
      sq += a * a;
    }
#pragma unroll
    for (int d = 1; d < 64; d <<= 1) { s += __shfl_xor(s, d); sq += __shfl_xor(sq, d); }
    float mean = s * (1.0f / 512.0f);
    float var = sq * (1.0f / 512.0f) - mean * mean;
    float is = 1.0f / sqrtf(var + 1e-5f);
    int c = lane * 8;
    bf8 o0;
#pragma unroll
    for (int j = 0; j < 8; ++j)
      o0[j] = (short)f2bf((bf2f((u16)f0[j]) - mean) * is * ag_s[c + j] + ag_b[c + j]);
    *(bf8*)&As[row * AST + c] = o0;
  }
  __syncthreads();

  // ---- AG GEMM: h = ag = LN(feat) @ Wag^T (K=512, two halves of 8) ----
  {
    f32x4 acc = {0.f, 0.f, 0.f, 0.f};
#pragma unroll
    for (int i = 0; i < 8; ++i) {
      bf8 a = *(const bf8*)&As[lrow * AST + i * 32 + wq8];
      acc = mfma16(a, wp[i], acc);
      wp[i] = *(const bf8*)(WagW + 256 + i * 32);
    }
#pragma unroll
    for (int i = 0; i < 8; ++i) {
      bf8 a = *(const bf8*)&As[lrow * AST + 256 + i * 32 + wq8];
      acc = mfma16(a, wp[i], acc);
      wp[i] = *(const bf8*)(W1W + i * 32);
    }
#pragma unroll
    for (int r = 0; r < 4; ++r) {
      int rr = quad * 4 + r;
      Hs[rr * HST + wn + lrow] = acc[r];
    }
  }
  __syncthreads();

  // ---- out_x = LN(x + ag/sqrt2) (fused outx) ----
  {
    int c = lane * 4;
    f32x4 xv = *(const f32x4*)&x[(size_t)nrow * 256 + c];
    f32x4 hv = *(const f32x4*)&Hs[row * HST + c];
    f32x4 v;
#pragma unroll
    for (int e = 0; e < 4; ++e) v[e] = xv[e] + hv[e] * RSQRT2;
    float s = v[0] + v[1] + v[2] + v[3];
    float sq = v[0] * v[0] + v[1] * v[1] + v[2] * v[2] + v[3] * v[3];
#pragma unroll
    for (int d = 1; d < 64; d <<= 1) { s += __shfl_xor(s, d); sq += __shfl_xor(sq, d); }
    float mean = s * (1.0f / 256.0f);
    float var = sq * (1.0f / 256.0f) - mean * mean;
    float is = 1.0f / sqrtf(var + 1e-5f);
    f32x4 o;
#pragma unroll
    for (int e = 0; e < 4; ++e)
      o[e] = (v[e] - mean) * is * ens[c + e] + enb[c + e];
    *(f32x4*)&out_x[(size_t)nrow * 256 + c] = o;
  }

  // ---- 3 residual layers ----
  for (int layer = 0; layer < 3; ++layer) {
    {
      int c = lane * 4;
      f32x4 h0 = *(const f32x4*)&Hs[row * HST + c];
      float s = h0[0] + h0[1] + h0[2] + h0[3];
      float sq = h0[0] * h0[0] + h0[1] * h0[1] + h0[2] * h0[2] + h0[3] * h0[3];
#pragma unroll
      for (int d = 1; d < 64; d <<= 1) { s += __shfl_xor(s, d); sq += __shfl_xor(sq, d); }
      float mean = s * (1.0f / 256.0f);
      float var = sq * (1.0f / 256.0f) - mean * mean;
      float is = 1.0f / sqrtf(var + 1e-5f);
      const float* g = rls + layer * 256;
      const float* bb = rlb + layer * 256;
      bf4 o;
#pragma unroll
      for (int e = 0; e < 4; ++e)
        o[e] = (short)f2bf((h0[e] - mean) * is * g[c + e] + bb[c + e]);
      *(bf4*)&As[row * AST + c] = o;
    }
    __syncthreads();

    {
      f32x4 acc = {0.f, 0.f, 0.f, 0.f};
#pragma unroll
      for (int i = 0; i < 8; ++i) {
        bf8 a = *(const bf8*)&As[lrow * AST + i * 32 + wq8];
        acc = mfma16(a, wp[i], acc);
        wp[i] = *(const bf8*)(W2W + (size_t)layer * 65536 + i * 32);
      }
      float bi = rb1[layer * 256 + wn + lrow];
#pragma unroll
      for (int r = 0; r < 4; ++r) {
        int rr = quad * 4 + r;
        Ys[rr * YST + wn + lrow] = f2bf(fmaxf(acc[r] + bi, 0.f));
      }
    }
    __syncthreads();

    {
      f32x4 acc = {0.f, 0.f, 0.f, 0.f};
#pragma unroll
      for (int i = 0; i < 8; ++i) {
        bf8 a = *(const bf8*)&Ys[lrow * YST + i * 32 + wq8];
        acc = mfma16(a, wp[i], acc);
        if (layer < 2)
          wp[i] = *(const bf8*)(W1W + (size_t)(layer + 1) * 65536 + i * 32);
      }
      float bi = rb2[layer * 256 + wn + lrow];
#pragma unroll
      for (int r = 0; r < 4; ++r) {
        int rr = quad * 4 + r;
        float* h0 = &Hs[rr * HST + wn + lrow];
        *h0 = (*h0 + acc[r] + bi) * RSQRT2;
      }
    }
    __syncthreads();
  }

  // ---- head ----
  if (lane < 20) {
    const float* hrow = &Hs[row * HST];
    const float* wrow = hw + (size_t)lane * 256;
    float l0 = 0.f, l1 = 0.f, l2 = 0.f, l3 = 0.f;
    for (int k = 0; k < 256; k += 16) {
      f32x4 h0 = *(const f32x4*)&hrow[k];
      f32x4 h1 = *(const f32x4*)&hrow[k + 4];
      f32x4 h2 = *(const f32x4*)&hrow[k + 8];
      f32x4 h3 = *(const f32x4*)&hrow[k + 12];
      f32x4 w0 = *(const f32x4*)&wrow[k];
      f32x4 w1 = *(const f32x4*)&wrow[k + 4];
      f32x4 w2 = *(const f32x4*)&wrow[k + 8];
      f32x4 w3 = *(const f32x4*)&wrow[k + 12];
#pragma unroll
      for (int e = 0; e < 4; ++e) {
        l0 += h0[e] * w0[e];
        l1 += h1[e] * w1[e];
        l2 += h2[e] * w2[e];
        l3 += h3[e] * w3[e];
      }
    }
    out_lg[(size_t)nrow * 20 + lane] = l0 + l1 + l2 + l3 + hb[lane];
  }
}

// ------- outx for rows NOT covered by pm (inv[n] < 0): out_x = LN(x) --------
__global__ __launch_bounds__(256) void outx_k(
    const float* __restrict__ x, const int* __restrict__ inv,
    const float* __restrict__ g, const float* __restrict__ bb,
    float* __restrict__ out, int N) {
  __shared__ float red[256];
  int tid = threadIdx.x;
  for (int n = blockIdx.x; n < N; n += gridDim.x) {
    if (inv[n] >= 0) continue;  // covered rows written by mlp_unpack
    __syncthreads();
    float v = x[(size_t)n * 256 + tid];
    red[tid] = v;
    __syncthreads();
    for (int off = 128; off; off >>= 1) {
      if (tid < off) red[tid] += red[tid + off];
      __syncthreads();
    }
    float mean = red[0] * (1.0f / 256.0f);
    __syncthreads();
    red[tid] = v * v;
    __syncthreads();
    for (int off = 128; off; off >>= 1) {
      if (tid < off) red[tid] += red[tid + off];
      __syncthreads();
    }
    float var = red[0] * (1.0f / 256.0f) - mean * mean;
    float is = 1.0f / sqrtf(var + 1e-5f);
    out[(size_t)n * 256 + tid] = (v - mean) * is * g[tid] + bb[tid];
    __syncthreads();
  }
}

// -----------------------------------------------------------------------------
extern "C" void kernel_launch(void* const* d_in, const int* in_sizes, int n_in,
                              void* d_out, int out_size, void* d_ws,
                              size_t ws_size, hipStream_t stream) {
  const float* x = (const float*)d_in[0];
  const float* emb = (const float*)d_in[1];
  const float* mask = (const float*)d_in[2];
  const int* pm = (const int*)d_in[3];
  const int* batch = (const int*)d_in[4];
  const float* Wq = (const float*)d_in[5];
  const float* Wk = (const float*)d_in[6];
  const float* Wv = (const float*)d_in[7];
  const float* ag_s = (const float*)d_in[8];
  const float* ag_b = (const float*)d_in[9];
  const float* Wag = (const float*)d_in[10];
  const float* rls = (const float*)d_in[11];
  const float* rlb = (const float*)d_in[12];
  const float* rw1 = (const float*)d_in[13];
  const float* rb1 = (const float*)d_in[14];
  const float* rw2 = (const float*)d_in[15];
  const float* rb2 = (const float*)d_in[16];
  const float* hw = (const float*)d_in[17];
  const float* hb = (const float*)d_in[18];
  const float* ens = (const float*)d_in[19];
  const float* enb = (const float*)d_in[20];

  const int N = in_sizes[0] / 256;  // 4096
  const int B = in_sizes[2] / 512;  // 4

  char* wsb = (char*)d_ws;
  // conversion-phase (dead before packed is written):
  u16* embbf = (u16*)(wsb + 0);
  u16* xbf   = (u16*)(wsb + 5242880);
  u16* Wkvbf = (u16*)(wsb + 7340032);
  u16* Wqbf  = (u16*)(wsb + 9961472);
  // attention phase:
  u16* packed = (u16*)(wsb + 0);           // 32 MB
  u16* KVbf   = (u16*)(wsb + 33554432);    // 4 MB (K half used; V half dead)
  u16* Qbf    = (u16*)(wsb + 37748736);    // 4 MB
  u16* VT     = (u16*)(wsb + 41943040);    // 2 MB
  u16* featE  = (u16*)(wsb + 44040192);    // 4 MB
  // persistent:
  u16* Wagbf = (u16*)(wsb + 48234496);
  u16* rw1bf = (u16*)(wsb + 48496640);
  u16* rw2bf = (u16*)(wsb + 48889856);
  int* list  = (int*)(wsb + 49545216);
  int* inv   = (int*)(wsb + 49610752);
  int* cnt   = (int*)(wsb + 49627136);

  float* out_x = (float*)d_out;
  float* out_lg = out_x + (size_t)N * 256;
  float* out_sc = out_lg + (size_t)N * 20;

  // 0. index init, then conversions + compaction (merged dispatch)
  init_idx_k<<<(B * N + 255) / 256, 256, 0, stream>>>(list, inv, cnt, N, B);
  CvtArgs ca;
  ca.d[0] = {emb, embbf, B * 512 * 1280};
  ca.d[1] = {x, xbf, 4096 * 256};
  ca.d[2] = {Wk, Wkvbf, 512 * 1280};
  ca.d[3] = {Wv, Wkvbf + 512 * 1280, 512 * 1280};
  ca.d[4] = {Wq, Wqbf, 512 * 256};
  ca.d[5] = {Wag, Wagbf, 256 * 512};
  ca.d[6] = {rw1, rw1bf, 3 * 256 * 256};
  ca.d[7] = {rw2, rw2bf, 3 * 256 * 256};
  {
    int acc = 0;
    for (int k = 0; k < 8; ++k) {
      ca.blk0[k] = acc;
      acc += (ca.d[k].n / 8 + 255) / 256;
    }
    ca.blk0[8] = acc;
    const int ncompact = (N + 255) / 256;  // 16
    cvt_k<<<acc + ncompact, 256, 0, stream>>>(ca, pm, batch, list, inv, cnt, N);
  }

  // 1+2. merged KV projection (V written transposed to VT) + Q projection
  const int nkv = (B * 512 / 64) * 16;  // 512
  const int nq = (N / 64) * 8;          // 512
  qkvproj_k<<<nkv + nq, 256, 0, stream>>>(
      embbf, Wkvbf, KVbf, VT, xbf, Wqbf, Qbf, pm, B * 512, N, nkv);

  // 3. fused attention (scores+softmax+PV), SBLK=128
  attn_fused<<<dim3(N / 32, B * 8), 256, 0, stream>>>(
      Qbf, KVbf, VT, list, mask, packed, featE, N);

  // 4-7 + unpack in ONE dispatch
  const int nmlp = N / 16;                 // 256
  const int nunp = N / 4;                  // 1024
  mlp_unpack<<<dim3(nmlp + nunp), 1024, 0, stream>>>(
      featE, ag_s, ag_b, Wagbf, x, ens, enb, rls, rlb, rw1bf, rb1,
      rw2bf, rb2, hw, hb, pm, packed, out_sc, out_lg, out_x, nmlp, N);

  // 7b. out_x for rows not covered by pm (row-loop, 64 blocks)
  outx_k<<<64, 256, 0, stream>>>(x, inv, ens, enb, out_x, N);
}

// Round 17
// 279.530 us; speedup vs baseline: 1.0199x; 1.0199x over previous
//
#include <hip/hip_runtime.h>
#include <math.h>

// Round 22: REVERT to round-20 exactly (best = 281.9us). Round-21's SBLK=128
// fired its falsifier (285.1): barrier-granularity in attn is exhausted.
// This configuration: staged 64-row attn tiles + XCD swizzle + T14 reg
// prefetch + ev-cache; vtrans folded into qkvproj (transposed V epilogue);
// mlp+unpack co-scheduled in one dispatch; cvt+compact merged; 6 dispatches.

typedef short bf8 __attribute__((ext_vector_type(8)));
typedef short bf4 __attribute__((ext_vector_type(4)));
typedef float f32x4 __attribute__((ext_vector_type(4)));
typedef unsigned short u16;

constexpr int LDT = 40;  // LDS row stride in shorts (32 data + 8 pad)
#define RSQRT2 0.70710678118654752f

__device__ __forceinline__ u16 f2bf(float f) {
  unsigned int u = __builtin_bit_cast(unsigned int, f);
  unsigned int r = u + 0x7fffu + ((u >> 16) & 1u);  // RNE
  return (u16)(r >> 16);
}
__device__ __forceinline__ float bf2f(u16 v) {
  return __builtin_bit_cast(float, (unsigned int)v << 16);
}
__device__ __forceinline__ f32x4 mfma16(bf8 a, bf8 b, f32x4 c) {
  return __builtin_amdgcn_mfma_f32_16x16x32_bf16(a, b, c, 0, 0, 0);
}

// ------- batched f32 -> bf16 conversion + index compaction (merged) ---------
struct CvtDesc { const float* src; u16* dst; int n; };
struct CvtArgs { CvtDesc d[8]; int blk0[9]; };  // blk0: prefix block starts

__global__ __launch_bounds__(256) void cvt_k(
    CvtArgs a, const int* __restrict__ pm, const int* __restrict__ batch,
    int* __restrict__ list, int* __restrict__ inv, int* __restrict__ cnt,
    int N) {
  const int blk = blockIdx.x;
  if (blk >= a.blk0[8]) {  // ---- compact tail blocks ----
    int m = (blk - a.blk0[8]) * 256 + threadIdx.x;
    if (m >= N) return;
    int p = pm[m];
    int b = batch[p];
    int slot = atomicAdd(&cnt[b], 1);
    list[(size_t)b * N + slot] = m;
    inv[p] = m;
    return;
  }
  int d = 0;
#pragma unroll
  for (int k = 1; k < 8; ++k)
    if (blk >= a.blk0[k]) d = k;
  CvtDesc dd = a.d[d];
  int i = ((blk - a.blk0[d]) * 256 + threadIdx.x) * 8;
  if (i >= dd.n) return;
  f32x4 v0 = *(const f32x4*)(dd.src + i);
  f32x4 v1 = *(const f32x4*)(dd.src + i + 4);
  bf8 o;
  o[0] = (short)f2bf(v0[0]); o[1] = (short)f2bf(v0[1]);
  o[2] = (short)f2bf(v0[2]); o[3] = (short)f2bf(v0[3]);
  o[4] = (short)f2bf(v1[0]); o[5] = (short)f2bf(v1[1]);
  o[6] = (short)f2bf(v1[2]); o[7] = (short)f2bf(v1[3]);
  *(bf8*)(dd.dst + i) = o;
}

// ---------------- index init (list=-1, inv=-1, cnt=0) ------------------------
__global__ void init_idx_k(int* __restrict__ list, int* __restrict__ inv,
                           int* __restrict__ cnt, int N, int B) {
  int i = blockIdx.x * 256 + threadIdx.x;
  if (i < B * N) list[i] = -1;
  if (i < N) inv[i] = -1;
  if (i < B) cnt[i] = 0;
}

// ------- 64x64-tile bf16 GEMM body (dbuf LDS + reg prefetch) -----------------
// C[M,Nn](bf16) = A[M,K](bf16, optional row gather) @ B[Nn,K](bf16)^T
// If VTout != nullptr: cols >= 512 are written TRANSPOSED into VTout as
// VTout[((row>>9)*512 + col-512)*512 + (row&511)] (one bf4 store per (i,j)).
__device__ __forceinline__ void proj64_body(
    u16 (*As)[64 * LDT], u16 (*Bs)[64 * LDT],
    const u16* __restrict__ A, const u16* __restrict__ B,
    u16* __restrict__ C, int M, int Nn, int K, int lda, int ldb, int ldc,
    const int* __restrict__ gatherA, int m0, int n0, u16* __restrict__ VTout) {
  const int tid = threadIdx.x;
  const int wave = tid >> 6, lane = tid & 63;
  const int wm = (wave & 1) * 32, wn = (wave >> 1) * 32;
  const int lrow = lane & 15, quad = lane >> 4;
  const int srow = tid >> 2, skq = tid & 3;
  const bf8 z8 = {0, 0, 0, 0, 0, 0, 0, 0};
  const int off = srow * LDT + skq * 8;

  int gr0 = m0 + srow;
  int ar0 = (gr0 < M) ? (gatherA ? gatherA[gr0] : gr0) : -1;
  const u16* Ap0 = (ar0 >= 0) ? A + (size_t)ar0 * lda + skq * 8 : nullptr;
  const u16* Bp = (n0 + srow < Nn) ? B + (size_t)(n0 + srow) * ldb + skq * 8 : nullptr;

  // prologue: stage k=0 into buffer 0
  {
    bf8 a0 = Ap0 ? *(const bf8*)Ap0 : z8;
    bf8 bv = Bp ? *(const bf8*)Bp : z8;
    *(bf8*)&As[0][off] = a0;
    *(bf8*)&Bs[0][off] = bv;
  }
  __syncthreads();

  f32x4 acc[2][2];
#pragma unroll
  for (int i = 0; i < 2; ++i)
#pragma unroll
    for (int j = 0; j < 2; ++j) acc[i][j] = (f32x4){0.f, 0.f, 0.f, 0.f};

  int cur = 0;
  for (int k0 = 0; k0 < K; k0 += 32) {
    const bool more = (k0 + 32 < K);
    bf8 na, nb;
    if (more) {  // issue next-tile loads; consumed after the MFMAs
      na = Ap0 ? *(const bf8*)(Ap0 + k0 + 32) : z8;
      nb = Bp ? *(const bf8*)(Bp + k0 + 32) : z8;
    }
    bf8 af0 = *(const bf8*)&As[cur][(wm + lrow) * LDT + quad * 8];
    bf8 af1 = *(const bf8*)&As[cur][(wm + 16 + lrow) * LDT + quad * 8];
    bf8 bf0 = *(const bf8*)&Bs[cur][(wn + lrow) * LDT + quad * 8];
    bf8 bf1 = *(const bf8*)&Bs[cur][(wn + 16 + lrow) * LDT + quad * 8];
    acc[0][0] = mfma16(af0, bf0, acc[0][0]);
    acc[0][1] = mfma16(af0, bf1, acc[0][1]);
    acc[1][0] = mfma16(af1, bf0, acc[1][0]);
    acc[1][1] = mfma16(af1, bf1, acc[1][1]);
    if (more) {  // write next tile into the OTHER buffer (no fence needed)
      *(bf8*)&As[cur ^ 1][off] = na;
      *(bf8*)&Bs[cur ^ 1][off] = nb;
    }
    __syncthreads();
    cur ^= 1;
  }

#pragma unroll
  for (int i = 0; i < 2; ++i) {
    const int row0 = m0 + wm + i * 16 + quad * 4;  // r = 0..3 consecutive
#pragma unroll
    for (int j = 0; j < 2; ++j) {
      int col = n0 + wn + j * 16 + lrow;
      if (col >= Nn) continue;
      if (VTout && col >= 512) {
        // transposed V write: 4 consecutive s positions -> one 8B store
        if (row0 < M) {
          int b = row0 >> 9, sl = row0 & 511;
          bf4 o;
#pragma unroll
          for (int r = 0; r < 4; ++r) o[r] = (short)f2bf(acc[i][j][r]);
          *(bf4*)&VTout[((size_t)(b * 512 + (col - 512)) * 512) + sl] = o;
        }
        continue;
      }
#pragma unroll
      for (int r = 0; r < 4; ++r) {
        int row = row0 + r;
        if (row >= M) continue;
        if (gatherA && gatherA[row] < 0) continue;
        C[(size_t)row * ldc + col] = f2bf(acc[i][j][r]);
      }
    }
  }
}

// ------- merged KV-proj (blocks [0,512)) + Q-proj (blocks [512,1024)) -------
__global__ __launch_bounds__(256) void qkvproj_k(
    const u16* __restrict__ embbf, const u16* __restrict__ Wkvbf,
    u16* __restrict__ KVbf, u16* __restrict__ VT,
    const u16* __restrict__ xbf, const u16* __restrict__ Wqbf,
    u16* __restrict__ Qbf, const int* __restrict__ pm,
    int MKV, int N, int nkv) {
  __shared__ __align__(16) u16 As[2][64 * LDT];
  __shared__ __align__(16) u16 Bs[2][64 * LDT];
  const int blk = blockIdx.x;
  if (blk < nkv) {  // KV: MKV x 1024, K=1280; n-tiles = 16 (8 K + 8 V)
    int by = blk >> 4, bx = blk & 15;
    proj64_body(As, Bs, embbf, Wkvbf, KVbf, MKV, 1024, 1280, 1280, 1280, 1024,
                nullptr, by * 64, bx * 64, VT);
  } else {          // Q: N x 512, K=256, gather pm; n-tiles = 8
    int t = blk - nkv;
    int by = t >> 3, bx = t & 7;
    proj64_body(As, Bs, xbf, Wqbf, Qbf, N, 512, 256, 256, 256, 512,
                pm, by * 64, bx * 64, nullptr);
  }
}

// ---------------- fused attention: per (b,h,mtile32) -------------------------
// Round-15 staged structure + XCD swizzle.
constexpr int WST = 520;  // W row stride (512 + 8 pad) -> 65 granules (odd)
constexpr int QST = 72;   // Q/K/V row stride (64 + 8 pad) -> 9 granules (odd)

__global__ __launch_bounds__(256) void attn_fused(
    const u16* __restrict__ Q, const u16* __restrict__ KV,
    const u16* __restrict__ VT, const int* __restrict__ list,
    const float* __restrict__ mask, u16* __restrict__ packed,
    u16* __restrict__ feat, int N) {
  const int NMT = gridDim.x;              // mt tiles per (b,h)
  const int lin = blockIdx.y * NMT + blockIdx.x;
  const int xcd = lin & 7, rest = lin >> 3;
  const int mt = rest % NMT;
  const int y = ((rest / NMT) << 3) | xcd;
  const int b = y >> 3, h = y & 7;
  const int* lst = list + (size_t)b * N + mt * 32;
  if (lst[0] < 0) return;

  __shared__ __align__(16) u16 Ws[32 * WST];
  __shared__ __align__(16) u16 Qs[32 * QST];
  __shared__ __align__(16) u16 KVs[64 * QST];  // K tiles (A) / V chunks (B)
  __shared__ __align__(16) float mk[8][68];    // mask, padded
  __shared__ int mS[32];

  const int tid = threadIdx.x;
  const int wave = tid >> 6, lane = tid & 63;
  const int wm = (wave & 1) * 16, wns = (wave >> 1) * 32;
  const int lrow = lane & 15, quad = lane >> 4;
  const bf8 z8 = {0, 0, 0, 0, 0, 0, 0, 0};

  const int c0 = tid * 2, c1 = tid * 2 + 1;
  const int sr0 = c0 >> 3, kq0 = c0 & 7;
  const int sr1 = c1 >> 3, kq1 = c1 & 7;
  u16* kvw0 = &KVs[sr0 * QST + kq0 * 8];
  u16* kvw1 = &KVs[sr1 * QST + kq1 * 8];

  if (tid < 32) mS[tid] = lst[tid];
  {  // stage mask into padded layout (float2 per thread)
    int p = tid >> 5, j = (tid & 31) * 2;
    *(float2*)&mk[p][j] = *(const float2*)&mask[(size_t)b * 512 + p * 64 + j];
  }
  {  // stage Q tile: 32 rows x 64k
    int qr = tid >> 3, kq = tid & 7;
    int m = lst[qr];
    *(bf8*)&Qs[qr * QST + kq * 8] =
        (m >= 0) ? *(const bf8*)(Q + (size_t)m * 512 + h * 64 + kq * 8) : z8;
  }
  const u16* KVb = KV + (size_t)(b * 512) * 1024 + h * 64;
  {  // prologue: stage K tile rot(0)
    int sta = mt & 7;
    *(bf8*)kvw0 = *(const bf8*)(KVb + (size_t)(sta * 64 + sr0) * 1024 + kq0 * 8);
    *(bf8*)kvw1 = *(const bf8*)(KVb + (size_t)(sta * 64 + sr1) * 1024 + kq1 * 8);
  }
  __syncthreads();

  const bf8 qa0 = *(const bf8*)&Qs[(wm + lrow) * QST + 0 + quad * 8];
  const bf8 qa1 = *(const bf8*)&Qs[(wm + lrow) * QST + 32 + quad * 8];

  // ---- Phase A: scores; next tile loaded to regs under the MFMA (T14) ----
  bf8 r0, r1;
  for (int st = 0; st < 8; ++st) {
    const int sta = (st + mt) & 7;
    if (st < 7) {
      int nx = (st + 1 + mt) & 7;
      r0 = *(const bf8*)(KVb + (size_t)(nx * 64 + sr0) * 1024 + kq0 * 8);
      r1 = *(const bf8*)(KVb + (size_t)(nx * 64 + sr1) * 1024 + kq1 * 8);
    }
    f32x4 acc0 = {0.f, 0.f, 0.f, 0.f}, acc1 = acc0;
    {
      bf8 b00 = *(const bf8*)&KVs[(wns + lrow) * QST + quad * 8];
      bf8 b10 = *(const bf8*)&KVs[(wns + 16 + lrow) * QST + quad * 8];
      bf8 b01 = *(const bf8*)&KVs[(wns + lrow) * QST + 32 + quad * 8];
      bf8 b11 = *(const bf8*)&KVs[(wns + 16 + lrow) * QST + 32 + quad * 8];
      __builtin_amdgcn_s_setprio(1);
      acc0 = mfma16(qa0, b00, acc0);
      acc1 = mfma16(qa0, b10, acc1);
      acc0 = mfma16(qa1, b01, acc0);
      acc1 = mfma16(qa1, b11, acc1);
      __builtin_amdgcn_s_setprio(0);
    }
#pragma unroll
    for (int r = 0; r < 4; ++r) {
      int lr = wm + quad * 4 + r;
      Ws[lr * WST + sta * 64 + wns + lrow] = f2bf(acc0[r] * 0.125f);
      Ws[lr * WST + sta * 64 + wns + 16 + lrow] = f2bf(acc1[r] * 0.125f);
    }
    __syncthreads();
    if (st < 7) {
      *(bf8*)kvw0 = r0;
      *(bf8*)kvw1 = r1;
      __syncthreads();
    }
  }

  // Phase-B prologue: first V chunk loads issued BEFORE stats (hidden there)
  const u16* VTb = VT + (size_t)(b * 512 + h * 64) * 512;
  bf8 v0p = *(const bf8*)(VTb + (size_t)sr0 * 512 + ((mt & 7) << 6) + kq0 * 8);
  bf8 v1p = *(const bf8*)(VTb + (size_t)sr1 * 512 + ((mt & 7) << 6) + kq1 * 8);

  // ---- Stats + W rebuild: exp values cached in VGPRs across passes ----
  {
    const int row = tid >> 3, part = tid & 7;
    u16* wrow = &Ws[row * WST + part * 64];
    const int mm = mS[row];
    bf8 w[8];
    float mx = -1e30f;
#pragma unroll
    for (int v = 0; v < 8; ++v) {
      w[v] = *(const bf8*)(wrow + v * 8);
#pragma unroll
      for (int j = 0; j < 8; ++j) mx = fmaxf(mx, bf2f((u16)w[v][j]));
    }
    if (mm >= 0) {
      u16* prow = packed + ((size_t)h * N + mm) * 512 + part * 64;
#pragma unroll
      for (int v = 0; v < 8; ++v) *(bf8*)(prow + v * 8) = w[v];
    }
#pragma unroll
    for (int d = 1; d < 8; d <<= 1) mx = fmaxf(mx, __shfl_xor(mx, d));
    float ev[64];
    float se = 0.f, ms = 0.f;
#pragma unroll
    for (int v = 0; v < 8; ++v) {
      f32x4 m0 = *(const f32x4*)&mk[part][v * 8];
      f32x4 m1 = *(const f32x4*)&mk[part][v * 8 + 4];
#pragma unroll
      for (int j = 0; j < 8; ++j) {
        float e = __expf(bf2f((u16)w[v][j]) - mx);
        ev[v * 8 + j] = e;
        se += e;
        ms += e * (j < 4 ? m0[j] : m1[j - 4]);
      }
    }
#pragma unroll
    for (int d = 1; d < 8; d <<= 1) {
      se += __shfl_xor(se, d);
      ms += __shfl_xor(ms, d);
    }
    float iv = 1.0f / (ms + 1e-6f * se);
#pragma unroll
    for (int v = 0; v < 8; ++v) {
      f32x4 m0 = *(const f32x4*)&mk[part][v * 8];
      f32x4 m1 = *(const f32x4*)&mk[part][v * 8 + 4];
      bf8 o;
#pragma unroll
      for (int j = 0; j < 8; ++j)
        o[j] = (short)f2bf(ev[v * 8 + j] * (j < 4 ? m0[j] : m1[j - 4]) * iv);
      *(bf8*)(wrow + v * 8) = o;
    }
  }
  __syncthreads();
  *(bf8*)kvw0 = v0p;
  *(bf8*)kvw1 = v1p;
  __syncthreads();

  // ---- Phase B: feat = W @ VT^T (32m x 64d, K=512), reg-prefetched ----
  f32x4 acc0 = {0.f, 0.f, 0.f, 0.f}, acc1 = acc0;
  for (int ss = 0; ss < 8; ++ss) {
    const int s0 = ((ss + mt) & 7) << 6;
    if (ss < 7) {
      int nx = ((ss + 1 + mt) & 7) << 6;
      v0p = *(const bf8*)(VTb + (size_t)sr0 * 512 + nx + kq0 * 8);
      v1p = *(const bf8*)(VTb + (size_t)sr1 * 512 + nx + kq1 * 8);
    }
#pragma unroll
    for (int k0 = 0; k0 < 64; k0 += 32) {
      bf8 a = *(const bf8*)&Ws[(wm + lrow) * WST + s0 + k0 + quad * 8];
      bf8 b0 = *(const bf8*)&KVs[(wns + lrow) * QST + k0 + quad * 8];
      bf8 b1 = *(const bf8*)&KVs[(wns + 16 + lrow) * QST + k0 + quad * 8];
      __builtin_amdgcn_s_setprio(1);
      acc0 = mfma16(a, b0, acc0);
      acc1 = mfma16(a, b1, acc1);
      __builtin_amdgcn_s_setprio(0);
    }
    __syncthreads();
    if (ss < 7) {
      *(bf8*)kvw0 = v0p;
      *(bf8*)kvw1 = v1p;
      __syncthreads();
    }
  }
#pragma unroll
  for (int r = 0; r < 4; ++r) {
    int lr = wm + quad * 4 + r;
    int mm = mS[lr];
    if (mm < 0) continue;
    u16* frow = feat + (size_t)mm * 512 + h * 64;
    frow[wns + lrow] = f2bf(acc0[r]);
    frow[wns + 16 + lrow] = f2bf(acc1[r]);
  }
}

// ------- merged: mlp chain (blocks < nmlp) + unpack (blocks >= nmlp) ---------
constexpr int HST = 268;   // Hs row stride in floats (67 granules, odd)
constexpr int AST = 520;   // As row stride in shorts (65 granules, odd)
constexpr int YST = 280;   // Ys row stride in shorts (35 granules, odd)
constexpr int SMEM_BYTES = 16 * HST * 4 + 16 * AST * 2 + 16 * YST * 2;

__global__ __launch_bounds__(1024) void mlp_unpack(
    const u16* __restrict__ feat, const float* __restrict__ ag_s,
    const float* __restrict__ ag_b, const u16* __restrict__ Wag,
    const float* __restrict__ x, const float* __restrict__ ens,
    const float* __restrict__ enb, const float* __restrict__ rls,
    const float* __restrict__ rlb, const u16* __restrict__ rw1,
    const float* __restrict__ rb1, const u16* __restrict__ rw2,
    const float* __restrict__ rb2, const float* __restrict__ hw,
    const float* __restrict__ hb, const int* __restrict__ pm,
    const u16* __restrict__ packed, float* __restrict__ out_sc,
    float* __restrict__ out_lg, float* __restrict__ out_x,
    int nmlp, int N) {
  __shared__ __align__(16) char smem[SMEM_BYTES];
  const int tid = threadIdx.x;

  if (blockIdx.x >= nmlp) {
    // ---------------- unpack body: 4 m-rows, 256 threads each ----------------
    u16* Ls = (u16*)smem;  // [4][8*520]
    const int g = tid >> 8, t = tid & 255;
    const int m = (blockIdx.x - nmlp) * 4 + g;
    u16* Lg = Ls + g * (8 * 520);
    int h = t >> 5, c = (t & 31) * 16;
    const u16* row = packed + ((size_t)h * N + m) * 512 + c;
    *(bf8*)&Lg[h * 520 + c] = *(const bf8*)row;
    *(bf8*)&Lg[h * 520 + c + 8] = *(const bf8*)(row + 8);
    __syncthreads();
    float* orow = out_sc + (size_t)pm[m] * 4096;
#pragma unroll
    for (int i = 0; i < 16; ++i) {
      int e = t + i * 256;
      orow[e] = bf2f(Lg[(e & 7) * 520 + (e >> 3)]);
    }
    return;
  }

  // ------------------------------ mlp body -----------------------------------
  float* Hs = (float*)smem;
  u16* As = (u16*)(smem + 16 * HST * 4);
  u16* Ys = (u16*)(smem + 16 * HST * 4 + 16 * AST * 2);
  const int m0 = blockIdx.x * 16;
  const int wave = tid >> 6, lane = tid & 63;
  const int lrow = lane & 15, quad = lane >> 4;
  const int wn = wave * 16;
  const int row = wave;
  const int wq8 = quad * 8;
  const int nrow = pm[m0 + row];

  const u16* WagW = Wag + (size_t)(wn + lrow) * 512 + wq8;
  const u16* W1W = rw1 + (size_t)(wn + lrow) * 256 + wq8;
  const u16* W2W = rw2 + (size_t)(wn + lrow) * 256 + wq8;

  bf8 wp[8];
#pragma unroll
  for (int i = 0; i < 8; ++i) wp[i] = *(const bf8*)(WagW + i * 32);

  // ---- LN512(feat) -> As (bf16), 8 cols per lane ----
  {
    const u16* frow = feat + (size_t)(m0 + row) * 512 + lane * 8;
    bf8 f0 = *(const bf8*)frow;
    float s = 0.f, sq = 0.f;
#pragma unroll
    for (int j = 0; j < 8; ++j) {
      float a = bf2f((u16)f0[j]);
      s += a;
      sq += a * a;
    }
#pragma unroll
    for (int d = 1; d < 64; d <<= 1) { s += __shfl_xor(s, d); sq += __shfl_xor(sq, d); }
    float mean = s * (1.0f / 512.0f);
    float var = sq * (1.0f / 512.0f) - mean * mean;
    float is = 1.0f / sqrtf(var + 1e-5f);
    int c = lane * 8;
    bf8 o0;
#pragma unroll
    for (int j = 0; j < 8; ++j)
      o0[j] = (short)f2bf((bf2f((u16)f0[j]) - mean) * is * ag_s[c + j] + ag_b[c + j]);
    *(bf8*)&As[row * AST + c] = o0;
  }
  __syncthreads();

  // ---- AG GEMM: h = ag = LN(feat) @ Wag^T (K=512, two halves of 8) ----
  {
    f32x4 acc = {0.f, 0.f, 0.f, 0.f};
#pragma unroll
    for (int i = 0; i < 8; ++i) {
      bf8 a = *(const bf8*)&As[lrow * AST + i * 32 + wq8];
      acc = mfma16(a, wp[i], acc);
      wp[i] = *(const bf8*)(WagW + 256 + i * 32);
    }
#pragma unroll
    for (int i = 0; i < 8; ++i) {
      bf8 a = *(const bf8*)&As[lrow * AST + 256 + i * 32 + wq8];
      acc = mfma16(a, wp[i], acc);
      wp[i] = *(const bf8*)(W1W + i * 32);
    }
#pragma unroll
    for (int r = 0; r < 4; ++r) {
      int rr = quad * 4 + r;
      Hs[rr * HST + wn + lrow] = acc[r];
    }
  }
  __syncthreads();

  // ---- out_x = LN(x + ag/sqrt2) (fused outx) ----
  {
    int c = lane * 4;
    f32x4 xv = *(const f32x4*)&x[(size_t)nrow * 256 + c];
    f32x4 hv = *(const f32x4*)&Hs[row * HST + c];
    f32x4 v;
#pragma unroll
    for (int e = 0; e < 4; ++e) v[e] = xv[e] + hv[e] * RSQRT2;
    float s = v[0] + v[1] + v[2] + v[3];
    float sq = v[0] * v[0] + v[1] * v[1] + v[2] * v[2] + v[3] * v[3];
#pragma unroll
    for (int d = 1; d < 64; d <<= 1) { s += __shfl_xor(s, d); sq += __shfl_xor(sq, d); }
    float mean = s * (1.0f / 256.0f);
    float var = sq * (1.0f / 256.0f) - mean * mean;
    float is = 1.0f / sqrtf(var + 1e-5f);
    f32x4 o;
#pragma unroll
    for (int e = 0; e < 4; ++e)
      o[e] = (v[e] - mean) * is * ens[c + e] + enb[c + e];
    *(f32x4*)&out_x[(size_t)nrow * 256 + c] = o;
  }

  // ---- 3 residual layers ----
  for (int layer = 0; layer < 3; ++layer) {
    {
      int c = lane * 4;
      f32x4 h0 = *(const f32x4*)&Hs[row * HST + c];
      float s = h0[0] + h0[1] + h0[2] + h0[3];
      float sq = h0[0] * h0[0] + h0[1] * h0[1] + h0[2] * h0[2] + h0[3] * h0[3];
#pragma unroll
      for (int d = 1; d < 64; d <<= 1) { s += __shfl_xor(s, d); sq += __shfl_xor(sq, d); }
      float mean = s * (1.0f / 256.0f);
      float var = sq * (1.0f / 256.0f) - mean * mean;
      float is = 1.0f / sqrtf(var + 1e-5f);
      const float* g = rls + layer * 256;
      const float* bb = rlb + layer * 256;
      bf4 o;
#pragma unroll
      for (int e = 0; e < 4; ++e)
        o[e] = (short)f2bf((h0[e] - mean) * is * g[c + e] + bb[c + e]);
      *(bf4*)&As[row * AST + c] = o;
    }
    __syncthreads();

    {
      f32x4 acc = {0.f, 0.f, 0.f, 0.f};
#pragma unroll
      for (int i = 0; i < 8; ++i) {
        bf8 a = *(const bf8*)&As[lrow * AST + i * 32 + wq8];
        acc = mfma16(a, wp[i], acc);
        wp[i] = *(const bf8*)(W2W + (size_t)layer * 65536 + i * 32);
      }
      float bi = rb1[layer * 256 + wn + lrow];
#pragma unroll
      for (int r = 0; r < 4; ++r) {
        int rr = quad * 4 + r;
        Ys[rr * YST + wn + lrow] = f2bf(fmaxf(acc[r] + bi, 0.f));
      }
    }
    __syncthreads();

    {
      f32x4 acc = {0.f, 0.f, 0.f, 0.f};
#pragma unroll
      for (int i = 0; i < 8; ++i) {
        bf8 a = *(const bf8*)&Ys[lrow * YST + i * 32 + wq8];
        acc = mfma16(a, wp[i], acc);
        if (layer < 2)
          wp[i] = *(const bf8*)(W1W + (size_t)(layer + 1) * 65536 + i * 32);
      }
      float bi = rb2[layer * 256 + wn + lrow];
#pragma unroll
      for (int r = 0; r < 4; ++r) {
        int rr = quad * 4 + r;
        float* h0 = &Hs[rr * HST + wn + lrow];
        *h0 = (*h0 + acc[r] + bi) * RSQRT2;
      }
    }
    __syncthreads();
  }

  // ---- head ----
  if (lane < 20) {
    const float* hrow = &Hs[row * HST];
    const float* wrow = hw + (size_t)lane * 256;
    float l0 = 0.f, l1 = 0.f, l2 = 0.f, l3 = 0.f;
    for (int k = 0; k < 256; k += 16) {
      f32x4 h0 = *(const f32x4*)&hrow[k];
      f32x4 h1 = *(const f32x4*)&hrow[k + 4];
      f32x4 h2 = *(const f32x4*)&hrow[k + 8];
      f32x4 h3 = *(const f32x4*)&hrow[k + 12];
      f32x4 w0 = *(const f32x4*)&wrow[k];
      f32x4 w1 = *(const f32x4*)&wrow[k + 4];
      f32x4 w2 = *(const f32x4*)&wrow[k + 8];
      f32x4 w3 = *(const f32x4*)&wrow[k + 12];
#pragma unroll
      for (int e = 0; e < 4; ++e) {
        l0 += h0[e] * w0[e];
        l1 += h1[e] * w1[e];
        l2 += h2[e] * w2[e];
        l3 += h3[e] * w3[e];
      }
    }
    out_lg[(size_t)nrow * 20 + lane] = l0 + l1 + l2 + l3 + hb[lane];
  }
}

// ------- outx for rows NOT covered by pm (inv[n] < 0): out_x = LN(x) --------
__global__ __launch_bounds__(256) void outx_k(
    const float* __restrict__ x, const int* __restrict__ inv,
    const float* __restrict__ g, const float* __restrict__ bb,
    float* __restrict__ out, int N) {
  __shared__ float red[256];
  int tid = threadIdx.x;
  for (int n = blockIdx.x; n < N; n += gridDim.x) {
    if (inv[n] >= 0) continue;  // covered rows written by mlp_unpack
    __syncthreads();
    float v = x[(size_t)n * 256 + tid];
    red[tid] = v;
    __syncthreads();
    for (int off = 128; off; off >>= 1) {
      if (tid < off) red[tid] += red[tid + off];
      __syncthreads();
    }
    float mean = red[0] * (1.0f / 256.0f);
    __syncthreads();
    red[tid] = v * v;
    __syncthreads();
    for (int off = 128; off; off >>= 1) {
      if (tid < off) red[tid] += red[tid + off];
      __syncthreads();
    }
    float var = red[0] * (1.0f / 256.0f) - mean * mean;
    float is = 1.0f / sqrtf(var + 1e-5f);
    out[(size_t)n * 256 + tid] = (v - mean) * is * g[tid] + bb[tid];
    __syncthreads();
  }
}

// -----------------------------------------------------------------------------
extern "C" void kernel_launch(void* const* d_in, const int* in_sizes, int n_in,
                              void* d_out, int out_size, void* d_ws,
                              size_t ws_size, hipStream_t stream) {
  const float* x = (const float*)d_in[0];
  const float* emb = (const float*)d_in[1];
  const float* mask = (const float*)d_in[2];
  const int* pm = (const int*)d_in[3];
  const int* batch = (const int*)d_in[4];
  const float* Wq = (const float*)d_in[5];
  const float* Wk = (const float*)d_in[6];
  const float* Wv = (const float*)d_in[7];
  const float* ag_s = (const float*)d_in[8];
  const float* ag_b = (const float*)d_in[9];
  const float* Wag = (const float*)d_in[10];
  const float* rls = (const float*)d_in[11];
  const float* rlb = (const float*)d_in[12];
  const float* rw1 = (const float*)d_in[13];
  const float* rb1 = (const float*)d_in[14];
  const float* rw2 = (const float*)d_in[15];
  const float* rb2 = (const float*)d_in[16];
  const float* hw = (const float*)d_in[17];
  const float* hb = (const float*)d_in[18];
  const float* ens = (const float*)d_in[19];
  const float* enb = (const float*)d_in[20];

  const int N = in_sizes[0] / 256;  // 4096
  const int B = in_sizes[2] / 512;  // 4

  char* wsb = (char*)d_ws;
  // conversion-phase (dead before packed is written):
  u16* embbf = (u16*)(wsb + 0);
  u16* xbf   = (u16*)(wsb + 5242880);
  u16* Wkvbf = (u16*)(wsb + 7340032);
  u16* Wqbf  = (u16*)(wsb + 9961472);
  // attention phase:
  u16* packed = (u16*)(wsb + 0);           // 32 MB
  u16* KVbf   = (u16*)(wsb + 33554432);    // 4 MB (K half used; V half dead)
  u16* Qbf    = (u16*)(wsb + 37748736);    // 4 MB
  u16* VT     = (u16*)(wsb + 41943040);    // 2 MB
  u16* featE  = (u16*)(wsb + 44040192);    // 4 MB
  // persistent:
  u16* Wagbf = (u16*)(wsb + 48234496);
  u16* rw1bf = (u16*)(wsb + 48496640);
  u16* rw2bf = (u16*)(wsb + 48889856);
  int* list  = (int*)(wsb + 49545216);
  int* inv   = (int*)(wsb + 49610752);
  int* cnt   = (int*)(wsb + 49627136);

  float* out_x = (float*)d_out;
  float* out_lg = out_x + (size_t)N * 256;
  float* out_sc = out_lg + (size_t)N * 20;

  // 0. index init, then conversions + compaction (merged dispatch)
  init_idx_k<<<(B * N + 255) / 256, 256, 0, stream>>>(list, inv, cnt, N, B);
  CvtArgs ca;
  ca.d[0] = {emb, embbf, B * 512 * 1280};
  ca.d[1] = {x, xbf, 4096 * 256};
  ca.d[2] = {Wk, Wkvbf, 512 * 1280};
  ca.d[3] = {Wv, Wkvbf + 512 * 1280, 512 * 1280};
  ca.d[4] = {Wq, Wqbf, 512 * 256};
  ca.d[5] = {Wag, Wagbf, 256 * 512};
  ca.d[6] = {rw1, rw1bf, 3 * 256 * 256};
  ca.d[7] = {rw2, rw2bf, 3 * 256 * 256};
  {
    int acc = 0;
    for (int k = 0; k < 8; ++k) {
      ca.blk0[k] = acc;
      acc += (ca.d[k].n / 8 + 255) / 256;
    }
    ca.blk0[8] = acc;
    const int ncompact = (N + 255) / 256;  // 16
    cvt_k<<<acc + ncompact, 256, 0, stream>>>(ca, pm, batch, list, inv, cnt, N);
  }

  // 1+2. merged KV projection (V written transposed to VT) + Q projection
  const int nkv = (B * 512 / 64) * 16;  // 512
  const int nq = (N / 64) * 8;          // 512
  qkvproj_k<<<nkv + nq, 256, 0, stream>>>(
      embbf, Wkvbf, KVbf, VT, xbf, Wqbf, Qbf, pm, B * 512, N, nkv);

  // 3. fused attention (scores+softmax+PV)
  attn_fused<<<dim3(N / 32, B * 8), 256, 0, stream>>>(
      Qbf, KVbf, VT, list, mask, packed, featE, N);

  // 4-7 + unpack in ONE dispatch
  const int nmlp = N / 16;                 // 256
  const int nunp = N / 4;                  // 1024
  mlp_unpack<<<dim3(nmlp + nunp), 1024, 0, stream>>>(
      featE, ag_s, ag_b, Wagbf, x, ens, enb, rls, rlb, rw1bf, rb1,
      rw2bf, rb2, hw, hb, pm, packed, out_sc, out_lg, out_x, nmlp, N);

  // 7b. out_x for rows not covered by pm (row-loop, 64 blocks)
  outx_k<<<64, 256, 0, stream>>>(x, inv, ens, enb, out_x, N);
}